// Round 1
// baseline (484.273 us; speedup 1.0000x reference)
//
#include <hip/hip_runtime.h>
#include <hip/hip_bf16.h>

// IDCST2: out = C0 @ (x @ S1^T), M=N=4096, fp32 in/out.
// Both matmuls expressed as D = A @ B^T (row-major A[M,K], B[N,K]):
//   GEMM1: yT = S1 @ x^T   (A=S1, B=x)     -> bf16 workspace
//   GEMM2: out = C0 @ yT^T (A=C0, B=yT)    -> f32 d_out
// bf16 MFMA (16x16x32), m97-style 128x128x32 tile, global_load_lds width=16.

#define KDIM 4096
#define BM 128
#define BN 128
#define BKT 32

typedef __bf16 bf8_t __attribute__((ext_vector_type(8)));
typedef float f4_t __attribute__((ext_vector_type(4)));

__device__ __forceinline__ void async_ld16(__bf16* lds, const __bf16* g) {
    __builtin_amdgcn_global_load_lds(
        (const __attribute__((address_space(1))) void*)g,
        (__attribute__((address_space(3))) void*)lds, 16, 0, 0);
}

// ---------------- basis generation ----------------
// C0[u,p] = cos(pi*(2u+1)*p/8192), S1[v,q] = sin(pi*(2v+1)*q/8192).
// Exact integer reduction mod 16384 (period) keeps the float arg in [0,2pi).
__global__ __launch_bounds__(256) void gen_cos_k(__bf16* __restrict__ out) {
    int i = blockIdx.x * 256 + threadIdx.x;      // each thread -> 8 elements
    int base = i * 8;
    int u = base >> 12;
    int p0 = base & 4095;
    unsigned f = (unsigned)(2 * u + 1);
    bf8_t o;
#pragma unroll
    for (int t = 0; t < 8; ++t) {
        unsigned prod = (f * (unsigned)(p0 + t)) & 16383u;   // mod 16384
        float ang = (float)prod * 3.8349519697141029e-4f;    // 2*pi/16384
        o[t] = (__bf16)__cosf(ang);
    }
    ((bf8_t*)out)[i] = o;
}

__global__ __launch_bounds__(256) void gen_sin_k(__bf16* __restrict__ out) {
    int i = blockIdx.x * 256 + threadIdx.x;
    int base = i * 8;
    int v = base >> 12;
    int q0 = base & 4095;
    unsigned f = (unsigned)(2 * v + 1);
    bf8_t o;
#pragma unroll
    for (int t = 0; t < 8; ++t) {
        unsigned prod = (f * (unsigned)(q0 + t)) & 16383u;
        float ang = (float)prod * 3.8349519697141029e-4f;
        o[t] = (__bf16)__sinf(ang);
    }
    ((bf8_t*)out)[i] = o;
}

// ---------------- f32 -> bf16 convert ----------------
__global__ __launch_bounds__(256) void cvt_f32_bf16_k(const float* __restrict__ in,
                                                      __bf16* __restrict__ out) {
    int i = blockIdx.x * 256 + threadIdx.x;      // each thread -> 8 elements
    const float4* in4 = (const float4*)in;
    float4 a = in4[2 * i];
    float4 b = in4[2 * i + 1];
    bf8_t v;
    v[0] = (__bf16)a.x; v[1] = (__bf16)a.y; v[2] = (__bf16)a.z; v[3] = (__bf16)a.w;
    v[4] = (__bf16)b.x; v[5] = (__bf16)b.y; v[6] = (__bf16)b.z; v[7] = (__bf16)b.w;
    ((bf8_t*)out)[i] = v;
}

// ---------------- GEMM: D[i,j] = sum_k A[i,k]*B[j,k] ----------------
// 4096x4096x4096, A,B row-major bf16 with ld=4096. OutT = float or __bf16.
template <typename OutT>
__global__ __launch_bounds__(256) void gemm_bt(const __bf16* __restrict__ A,
                                               const __bf16* __restrict__ B,
                                               OutT* __restrict__ D) {
    __shared__ __bf16 sA[BM * BKT];   // 8 KiB, row-major [128][32], NO padding
    __shared__ __bf16 sB[BN * BKT];   // (global_load_lds requires contiguity)

    const int tid = threadIdx.x;
    const int bx = blockIdx.x;        // N tile
    const int by = blockIdx.y;        // M tile

    // staging: thread t loads 8 bf16 (16 B); 2 issues per tile (64 rows each)
    const __bf16* gA = A + (size_t)(by * BM + (tid >> 2)) * KDIM + (tid & 3) * 8;
    const __bf16* gB = B + (size_t)(bx * BN + (tid >> 2)) * KDIM + (tid & 3) * 8;
    __bf16* lA = &sA[tid * 8];
    __bf16* lB = &sB[tid * 8];

    const int lane = tid & 63;
    const int wave = tid >> 6;
    const int waveM = (wave & 1) * 64;
    const int waveN = (wave >> 1) * 64;
    const int fm = lane & 15;          // fragment row
    const int fk = (lane >> 4) * 8;    // fragment k offset

    f4_t acc[4][4];
#pragma unroll
    for (int i = 0; i < 4; ++i)
#pragma unroll
        for (int j = 0; j < 4; ++j)
            acc[i][j] = (f4_t){0.f, 0.f, 0.f, 0.f};

    for (int kb = 0; kb < KDIM; kb += BKT) {
        async_ld16(lA,        gA + kb);
        async_ld16(lA + 2048, gA + kb + (size_t)64 * KDIM);
        async_ld16(lB,        gB + kb);
        async_ld16(lB + 2048, gB + kb + (size_t)64 * KDIM);
        __syncthreads();   // compiler emits vmcnt(0) drain before barrier

        bf8_t af[4], bfr[4];
#pragma unroll
        for (int i = 0; i < 4; ++i)
            af[i] = *(const bf8_t*)&sA[(waveM + i * 16 + fm) * BKT + fk];
#pragma unroll
        for (int j = 0; j < 4; ++j)
            bfr[j] = *(const bf8_t*)&sB[(waveN + j * 16 + fm) * BKT + fk];

#pragma unroll
        for (int i = 0; i < 4; ++i)
#pragma unroll
            for (int j = 0; j < 4; ++j)
                acc[i][j] = __builtin_amdgcn_mfma_f32_16x16x32_bf16(
                    af[i], bfr[j], acc[i][j], 0, 0, 0);
        __syncthreads();
    }

    // C/D layout: col = lane&15, row = (lane>>4)*4 + r  [verified m89/m91]
    const int orow0 = by * BM + waveM + (lane >> 4) * 4;
    const int ocol0 = bx * BN + waveN + fm;
#pragma unroll
    for (int i = 0; i < 4; ++i)
#pragma unroll
        for (int j = 0; j < 4; ++j)
#pragma unroll
            for (int r = 0; r < 4; ++r) {
                size_t idx = (size_t)(orow0 + i * 16 + r) * KDIM + (ocol0 + j * 16);
                D[idx] = (OutT)acc[i][j][r];
            }
}

extern "C" void kernel_launch(void* const* d_in, const int* in_sizes, int n_in,
                              void* d_out, int out_size, void* d_ws, size_t ws_size,
                              hipStream_t stream) {
    const float* x = (const float*)d_in[0];
    float* out = (float*)d_out;

    char* ws = (char*)d_ws;
    __bf16* xb    = (__bf16*)ws;                          // 32 MiB
    __bf16* basis = (__bf16*)(ws + ((size_t)32 << 20));   // 32 MiB (S1 then C0)
    __bf16* yT    = (__bf16*)(ws + ((size_t)64 << 20));   // 32 MiB

    const int n8blocks = (4096 * 4096 / 8) / 256;         // 8192
    dim3 ggrid(32, 32);

    cvt_f32_bf16_k<<<n8blocks, 256, 0, stream>>>(x, xb);
    gen_sin_k<<<n8blocks, 256, 0, stream>>>(basis);
    // GEMM1: yT[v,p] = sum_q S1[v,q] * x[p,q]
    gemm_bt<__bf16><<<ggrid, 256, 0, stream>>>(basis, xb, yT);
    gen_cos_k<<<n8blocks, 256, 0, stream>>>(basis);
    // GEMM2: out[u,v] = sum_p C0[u,p] * yT[v,p]
    gemm_bt<float><<<ggrid, 256, 0, stream>>>(basis, yT, out);
}

// Round 5
// 468.883 us; speedup vs baseline: 1.0328x; 1.0328x over previous
//
#include <hip/hip_runtime.h>
#include <hip/hip_bf16.h>

// IDCST2: out = C0 @ (x @ S1^T), M=N=4096, fp32 in/out.
// Both matmuls as D = A @ B^T (row-major A[M,K], B[N,K]):
//   GEMM1: yT = S1 @ x^T   (A=S1, B=x)     -> bf16 workspace
//   GEMM2: out = C0 @ yT^T (A=C0, B=yT)    -> f32 d_out
// bf16 MFMA 16x16x32, 128x128 tile. BK=64 realized as TWO independent
// 128x32 row-major slabs per operand (identical LDS read pattern to the
// proven BK=32 kernel), one barrier pair per 64-k: 32 MFMAs amortize each
// vmcnt(0) barrier drain. global_load_lds width=16 staging.

#define KDIM 4096
#define BM 128
#define BN 128

typedef __bf16 bf8_t __attribute__((ext_vector_type(8)));
typedef float f4_t __attribute__((ext_vector_type(4)));

__device__ __forceinline__ void async_ld16(__bf16* lds, const __bf16* g) {
    __builtin_amdgcn_global_load_lds(
        (const __attribute__((address_space(1))) void*)g,
        (__attribute__((address_space(3))) void*)lds, 16, 0, 0);
}

// ---------------- basis generation ----------------
// C0[u,p] = cos(pi*(2u+1)*p/8192), S1[v,q] = sin(pi*(2v+1)*q/8192).
// Exact integer reduction mod 16384 keeps the float arg in [0,2pi).
__global__ __launch_bounds__(256) void gen_cos_k(__bf16* __restrict__ out) {
    int i = blockIdx.x * 256 + threadIdx.x;
    int base = i * 8;
    int u = base >> 12;
    int p0 = base & 4095;
    unsigned f = (unsigned)(2 * u + 1);
    bf8_t o;
#pragma unroll
    for (int t = 0; t < 8; ++t) {
        unsigned prod = (f * (unsigned)(p0 + t)) & 16383u;
        float ang = (float)prod * 3.8349519697141029e-4f;   // 2*pi/16384
        o[t] = (__bf16)__cosf(ang);
    }
    ((bf8_t*)out)[i] = o;
}

__global__ __launch_bounds__(256) void gen_sin_k(__bf16* __restrict__ out) {
    int i = blockIdx.x * 256 + threadIdx.x;
    int base = i * 8;
    int v = base >> 12;
    int q0 = base & 4095;
    unsigned f = (unsigned)(2 * v + 1);
    bf8_t o;
#pragma unroll
    for (int t = 0; t < 8; ++t) {
        unsigned prod = (f * (unsigned)(q0 + t)) & 16383u;
        float ang = (float)prod * 3.8349519697141029e-4f;
        o[t] = (__bf16)__sinf(ang);
    }
    ((bf8_t*)out)[i] = o;
}

// ---------------- f32 -> bf16 convert ----------------
__global__ __launch_bounds__(256) void cvt_f32_bf16_k(const float* __restrict__ in,
                                                      __bf16* __restrict__ out) {
    int i = blockIdx.x * 256 + threadIdx.x;
    const float4* in4 = (const float4*)in;
    float4 a = in4[2 * i];
    float4 b = in4[2 * i + 1];
    bf8_t v;
    v[0] = (__bf16)a.x; v[1] = (__bf16)a.y; v[2] = (__bf16)a.z; v[3] = (__bf16)a.w;
    v[4] = (__bf16)b.x; v[5] = (__bf16)b.y; v[6] = (__bf16)b.z; v[7] = (__bf16)b.w;
    ((bf8_t*)out)[i] = v;
}

// ---------------- GEMM: D[i,j] = sum_k A[i,k]*B[j,k] ----------------
// 4096x4096x4096, A,B row-major bf16 ld=4096. OutT = float or __bf16.
template <typename OutT>
__global__ __launch_bounds__(256) void gemm_bt(const __bf16* __restrict__ A,
                                               const __bf16* __restrict__ B,
                                               OutT* __restrict__ D) {
    // two 128x32 row-major slabs per operand (h = k-half), 32 KiB total
    __shared__ __bf16 sA[2][BM * 32];
    __shared__ __bf16 sB[2][BN * 32];

    const int tid = threadIdx.x;
    const int bx = blockIdx.x;        // N tile
    const int by = blockIdx.y;        // M tile

    // staging (per 32-wide slab): thread t -> row t>>2, 16B chunk t&3;
    // LDS dest forced to tid*8 elements (wave-uniform base + lane*16B).
    const __bf16* gA = A + (size_t)(by * BM + (tid >> 2)) * KDIM + (tid & 3) * 8;
    const __bf16* gB = B + (size_t)(bx * BN + (tid >> 2)) * KDIM + (tid & 3) * 8;

    const int lane = tid & 63;
    const int wave = tid >> 6;
    const int waveM = (wave & 1) * 64;
    const int waveN = (wave >> 1) * 64;
    const int fm = lane & 15;          // fragment row within 16
    const int fk = (lane >> 4) * 8;    // fragment k offset within slab

    f4_t acc[4][4];
#pragma unroll
    for (int i = 0; i < 4; ++i)
#pragma unroll
        for (int j = 0; j < 4; ++j)
            acc[i][j] = (f4_t){0.f, 0.f, 0.f, 0.f};

    for (int kb = 0; kb < KDIM; kb += 64) {
#pragma unroll
        for (int h = 0; h < 2; ++h) {
            const int kc = kb + h * 32;
            async_ld16(&sA[h][tid * 8],        gA + kc);
            async_ld16(&sA[h][tid * 8 + 2048], gA + kc + (size_t)64 * KDIM);
            async_ld16(&sB[h][tid * 8],        gB + kc);
            async_ld16(&sB[h][tid * 8 + 2048], gB + kc + (size_t)64 * KDIM);
        }
        __syncthreads();   // single vmcnt(0) drain per 64-k; 32 MFMAs follow

#pragma unroll
        for (int h = 0; h < 2; ++h) {
            bf8_t af[4], bfr[4];
#pragma unroll
            for (int i = 0; i < 4; ++i)
                af[i] = *(const bf8_t*)&sA[h][(waveM + i * 16 + fm) * 32 + fk];
#pragma unroll
            for (int j = 0; j < 4; ++j)
                bfr[j] = *(const bf8_t*)&sB[h][(waveN + j * 16 + fm) * 32 + fk];

#pragma unroll
            for (int i = 0; i < 4; ++i)
#pragma unroll
                for (int j = 0; j < 4; ++j)
                    acc[i][j] = __builtin_amdgcn_mfma_f32_16x16x32_bf16(
                        af[i], bfr[j], acc[i][j], 0, 0, 0);
        }
        __syncthreads();
    }

    // C/D layout: col = lane&15, row = (lane>>4)*4 + r  [verified m89/m91]
    const int orow0 = by * BM + waveM + (lane >> 4) * 4;
    const int ocol0 = bx * BN + waveN + fm;
#pragma unroll
    for (int i = 0; i < 4; ++i)
#pragma unroll
        for (int j = 0; j < 4; ++j)
#pragma unroll
            for (int r = 0; r < 4; ++r) {
                size_t idx = (size_t)(orow0 + i * 16 + r) * KDIM + (ocol0 + j * 16);
                D[idx] = (OutT)acc[i][j][r];
            }
}

extern "C" void kernel_launch(void* const* d_in, const int* in_sizes, int n_in,
                              void* d_out, int out_size, void* d_ws, size_t ws_size,
                              hipStream_t stream) {
    const float* x = (const float*)d_in[0];
    float* out = (float*)d_out;

    char* ws = (char*)d_ws;
    __bf16* xb    = (__bf16*)ws;                          // 32 MiB
    __bf16* basis = (__bf16*)(ws + ((size_t)32 << 20));   // 32 MiB (S1 then C0)
    __bf16* yT    = (__bf16*)(ws + ((size_t)64 << 20));   // 32 MiB

    const int n8blocks = (4096 * 4096 / 8) / 256;         // 8192
    dim3 ggrid(32, 32);

    cvt_f32_bf16_k<<<n8blocks, 256, 0, stream>>>(x, xb);
    gen_sin_k<<<n8blocks, 256, 0, stream>>>(basis);
    // GEMM1: yT[v,p] = sum_q S1[v,q] * x[p,q]
    gemm_bt<__bf16><<<ggrid, 256, 0, stream>>>(basis, xb, yT);
    gen_cos_k<<<n8blocks, 256, 0, stream>>>(basis);
    // GEMM2: out[u,v] = sum_p C0[u,p] * yT[v,p]
    gemm_bt<float><<<ggrid, 256, 0, stream>>>(basis, yT, out);
}

// Round 7
// 237.199 us; speedup vs baseline: 2.0416x; 1.9768x over previous
//
#include <hip/hip_runtime.h>

// IDCST2 via FFTs: out = C0 @ (x @ S1^T), M=N=4096, fp32.
//   DST-III rows:  s_v = (-1)^v * DCT3(reverse(x))_v  (c_0 = 0)
//   DCT-III via N-pt complex DFT (inverse Makhoul):
//     W_k = (c_k - i c_{N-k}) e^{i pi k/2N};  v = DFT_+(W)
//     y_{2n} = (Re v_n + c_0)/2 ; y_{2n+1} = (Re v_{N-1-n} + c_0)/2
//   v is real for real c => pack 2 rows per complex FFT (Re/Im).
// FFT: radix-2 DIF Stockham, 12 stages, LDS ping-pong, natural order out.
// Pipeline: dst_rows(x->ws) ; T(ws->out) ; dct_rows(out->ws) ; T(ws->out).

#define NF 4096
#define HALF 2048
#define PI_8192 3.8349519697141029e-4f   // pi/8192
#define PI_2048 1.5339807878856412e-3f   // pi/2048

// ---- 12-stage radix-2 DIF Stockham on packed complex data in LDS ----
// butterfly: Y[2i-q] = a+b ; Y[2i-q+s] = (a-b)*e^{+i*pi*(i-q)/2048}, q=i&(s-1)
__device__ __forceinline__ void fft4096(float2* __restrict__ bufA,
                                        float2* __restrict__ bufB, int t) {
    float2* X = bufA;
    float2* Y = bufB;
    for (int s = 1; s < NF; s <<= 1) {
        __syncthreads();
#pragma unroll
        for (int u = 0; u < 8; ++u) {
            int idx = t + 256 * u;           // 0..2047
            int q = idx & (s - 1);
            float2 a = X[idx];
            float2 b = X[idx + HALF];
            float ang = (float)(idx - q) * PI_2048;
            float sn = __sinf(ang), cs = __cosf(ang);
            float dx = a.x - b.x, dy = a.y - b.y;
            Y[2 * idx - q]     = make_float2(a.x + b.x, a.y + b.y);
            Y[2 * idx - q + s] = make_float2(dx * cs - dy * sn,
                                             dx * sn + dy * cs);
        }
        float2* tmp = X; X = Y; Y = tmp;
    }
    __syncthreads();
    // 12 swaps (even): result is back in bufA, natural order.
}

// ---- stage 1: DST-III along rows; two rows per block ----
__global__ __launch_bounds__(256) void dst_rows_k(const float* __restrict__ x,
                                                  float* __restrict__ y) {
    __shared__ float2 bufA[NF];
    __shared__ float2 bufB[NF];
    const int t = threadIdx.x;
    const size_t r0 = (size_t)blockIdx.x * 2;
    const float* x0 = x + r0 * NF;
    const float* x1 = x0 + NF;

    // pack: c_p = x[N-p] (p>=1), c_0 = 0 (DST reversal), two rows Re/Im:
    // k>=1: W_k = [(x0[N-k]+x1[k]) + i(x1[N-k]-x0[k])] * e^{i pi k/8192}
#pragma unroll
    for (int u = 0; u < 16; ++u) {
        int k = t + 256 * u;
        float2 w = make_float2(0.f, 0.f);
        if (k > 0) {
            float re = x0[NF - k] + x1[k];
            float im = x1[NF - k] - x0[k];
            float ang = (float)k * PI_8192;
            float sn = __sinf(ang), cs = __cosf(ang);
            w = make_float2(re * cs - im * sn, re * sn + im * cs);
        }
        bufA[k] = w;
    }

    fft4096(bufA, bufB, t);

    // unpack with DST sign: y[2n] = Re v_n/2, y[2n+1] = -Re v_{N-1-n}/2
    float* y0 = y + r0 * NF;
    float* y1 = y0 + NF;
#pragma unroll
    for (int u = 0; u < 8; ++u) {
        int n = t + 256 * u;                 // 0..2047
        float2 vn = bufA[n];
        float2 vm = bufA[NF - 1 - n];
        ((float2*)y0)[n] = make_float2(0.5f * vn.x, -0.5f * vm.x);
        ((float2*)y1)[n] = make_float2(0.5f * vn.y, -0.5f * vm.y);
    }
}

// ---- stage 2: DCT-III along rows of yT; two rows per block ----
__global__ __launch_bounds__(256) void dct_rows_k(const float* __restrict__ yt,
                                                  float* __restrict__ ot) {
    __shared__ float2 bufA[NF];
    __shared__ float2 bufB[NF];
    const int t = threadIdx.x;
    const size_t r0 = (size_t)blockIdx.x * 2;
    const float* t0 = yt + r0 * NF;
    const float* t1 = t0 + NF;
    const float a0 = t0[0];
    const float a1 = t1[0];

    // pack (c_N := 0): k=0: W_0 = c0 + i c'0
    // k>=1: W_k = [(t0[k]+t1[N-k]) + i(t1[k]-t0[N-k])] * e^{i pi k/8192}
#pragma unroll
    for (int u = 0; u < 16; ++u) {
        int k = t + 256 * u;
        float2 w;
        if (k == 0) {
            w = make_float2(a0, a1);
        } else {
            float re = t0[k] + t1[NF - k];
            float im = t1[k] - t0[NF - k];
            float ang = (float)k * PI_8192;
            float sn = __sinf(ang), cs = __cosf(ang);
            w = make_float2(re * cs - im * sn, re * sn + im * cs);
        }
        bufA[k] = w;
    }

    fft4096(bufA, bufB, t);

    // unpack: o[2n] = (Re v_n + c0)/2, o[2n+1] = (Re v_{N-1-n} + c0)/2
    float* o0 = ot + r0 * NF;
    float* o1 = o0 + NF;
#pragma unroll
    for (int u = 0; u < 8; ++u) {
        int n = t + 256 * u;
        float2 vn = bufA[n];
        float2 vm = bufA[NF - 1 - n];
        ((float2*)o0)[n] = make_float2(0.5f * (vn.x + a0), 0.5f * (vm.x + a0));
        ((float2*)o1)[n] = make_float2(0.5f * (vn.y + a1), 0.5f * (vm.y + a1));
    }
}

// ---- 32x32 LDS-tiled transpose, float4 IO: out[c][r] = in[r][c] ----
__global__ __launch_bounds__(256) void transpose_k(const float* __restrict__ in,
                                                   float* __restrict__ out) {
    __shared__ float tile[32][33];
    const int tx = threadIdx.x;   // 0..7
    const int ty = threadIdx.y;   // 0..31
    const int c0 = blockIdx.x * 32;
    const int r0 = blockIdx.y * 32;

    float4 v = *(const float4*)(in + (size_t)(r0 + ty) * NF + c0 + 4 * tx);
    tile[ty][4 * tx + 0] = v.x;
    tile[ty][4 * tx + 1] = v.y;
    tile[ty][4 * tx + 2] = v.z;
    tile[ty][4 * tx + 3] = v.w;
    __syncthreads();

    float4 o;
    o.x = tile[4 * tx + 0][ty];
    o.y = tile[4 * tx + 1][ty];
    o.z = tile[4 * tx + 2][ty];
    o.w = tile[4 * tx + 3][ty];
    *(float4*)(out + (size_t)(c0 + ty) * NF + r0 + 4 * tx) = o;
}

extern "C" void kernel_launch(void* const* d_in, const int* in_sizes, int n_in,
                              void* d_out, int out_size, void* d_ws, size_t ws_size,
                              hipStream_t stream) {
    const float* x = (const float*)d_in[0];
    float* out = (float*)d_out;
    float* y = (float*)d_ws;               // 64 MiB scratch

    dim3 tgrid(128, 128), tblk(8, 32);

    // y[p,v] = DST3 rows of x
    dst_rows_k<<<2048, 256, 0, stream>>>(x, y);
    // out = yT
    transpose_k<<<tgrid, tblk, 0, stream>>>(y, out);
    // y[v,u] = DCT3 rows of yT  (= out[u,v] transposed)
    dct_rows_k<<<2048, 256, 0, stream>>>(out, y);
    // out[u,v]
    transpose_k<<<tgrid, tblk, 0, stream>>>(y, out);
}